// Round 1
// baseline (220.351 us; speedup 1.0000x reference)
//
#include <hip/hip_runtime.h>
#include <math.h>

#define T_TOKENS 8192
#define NEXP 64
#define HID 2048
#define NITER 30
#define SINK_BLOCKS 32
#define WREG 131072          // bf16 elements per W region (64 x 2048)

typedef __bf16 bf16_t;
typedef bf16_t bf16x8 __attribute__((ext_vector_type(8)));
typedef float  f32x4  __attribute__((ext_vector_type(4)));

__device__ __forceinline__ void gload_lds16(const void* g, void* l) {
    __builtin_amdgcn_global_load_lds(
        (const __attribute__((address_space(1))) unsigned int*)g,
        (__attribute__((address_space(3))) unsigned int*)l, 16, 0, 0);
}

// ---------------------------------------------------------------------------
// Kernel 0: W (64x2048 f32) -> hi/lo bf16, per-64k-chunk quad-XOR-swizzled,
// linear in the exact order gemm's global_load_lds consumes.
// chunk c (0..31), row r, slot s holds quad q = s ^ (r&7) of W[r][c*64..].
// ---------------------------------------------------------------------------
__global__ __launch_bounds__(256)
void prep_whl(const float* __restrict__ W, bf16_t* __restrict__ wsw)
{
    int gid = blockIdx.x * 256 + threadIdx.x;   // 0..32767
    int region = gid >> 14;                     // 0 = hi, 1 = lo
    int qid = gid & 16383;
    int c = qid >> 9, L = qid & 511;
    int r = L >> 3, slot = L & 7;
    int qi = slot ^ (r & 7);
    const float* src = W + (size_t)r * HID + c * 64 + qi * 8;
    float4 v0 = *(const float4*)src;
    float4 v1 = *(const float4*)(src + 4);
    float x[8] = {v0.x, v0.y, v0.z, v0.w, v1.x, v1.y, v1.z, v1.w};
    bf16x8 q;
#pragma unroll
    for (int i = 0; i < 8; i++) {
        bf16_t h = (bf16_t)x[i];
        q[i] = (region == 0) ? h : (bf16_t)(x[i] - (float)h);
    }
    *(bf16x8*)(wsw + (size_t)region * WREG + (size_t)qid * 8) = q;
}

// ---------------------------------------------------------------------------
// Kernel 1: split-K(2) MFMA GEMM. 512 blocks x 256 thr (4 waves).
// Block: 32 tokens x 64 experts x K-half 1024 (16 chunks of 64).
// ALL staging via global_load_lds(16B): A raw f32 (source-address swizzled),
// W prepped bf16. Wave (mgrp,ngrp) = 16 tok x 32 exp; 3-term split-bf16 MFMA.
//
// r1 change: depth-2 prefetch pipeline (3 LDS buffers) with RAW s_barrier +
// COUNTED vmcnt (T3+T4). The old __syncthreads drained vmcnt(0) every chunk,
// serializing the full HBM latency of the just-issued prefetch into each of
// the 16 chunk iterations. Now each wave waits only for its own chunk-cc
// loads (vmcnt(12) = 2 stages x 6 loads in flight), then barriers; prefetch
// loads stay in flight across barriers.
// ---------------------------------------------------------------------------
__global__ __launch_bounds__(256, 2)
void gemm_splitk(const float* __restrict__ A, const bf16_t* __restrict__ Wq,
                 float* __restrict__ part)
{
    __shared__ float  sA[3][32 * 64];       // 8 KB x3 (raw f32, swizzled chunks)
    __shared__ bf16_t sW[3][2][64 * 64];    // 8 KB x6 (hi/lo bf16, swizzled)

    const int tid = threadIdx.x, lane = tid & 63, wv = tid >> 6;
    const int ks   = blockIdx.x & 1;
    const int tok0 = (blockIdx.x >> 1) * 32;
    const int mgrp = wv >> 1, ngrp = wv & 1;
    const int g = lane >> 4, m = lane & 15;
    const int arow = mgrp * 16 + m;
    const int m7 = m & 7;

    f32x4 acc0 = {0.f, 0.f, 0.f, 0.f}, acc1 = {0.f, 0.f, 0.f, 0.f};

    // staging maps (2 A-instrs + 4 W-instrs per wave per chunk)
    int ap[2], acs[2];   // A: lds position block, swizzled source chunk
#pragma unroll
    for (int j = 0; j < 2; j++) {
        int p = (wv * 2 + j) * 64 + lane;          // 16B-position 0..511
        ap[j] = p;
        int r = p >> 4, slot = p & 15;
        acs[j] = slot ^ (r & 7);                   // source 16B-chunk within row
    }

#define STAGE_CHUNK(cc, dst)                                                    \
    {                                                                           \
        const int _cc = (cc);                                                   \
        const int _d  = (dst);                                                  \
        _Pragma("unroll")                                                       \
        for (int j = 0; j < 2; j++) {                                           \
            int r = ap[j] >> 4;                                                 \
            const float* src = A + (size_t)(tok0 + r) * HID + ks * 1024         \
                             + _cc * 64 + acs[j] * 4;                           \
            gload_lds16(src, &sA[_d][(wv * 2 + j) * 256]);                      \
        }                                                                       \
        const size_t chb = ((size_t)(ks * 16 + _cc) * 512) * 8;                 \
        _Pragma("unroll")                                                       \
        for (int j = 0; j < 2; j++) {                                           \
            size_t q8 = chb + (size_t)((wv * 2 + j) * 64 + lane) * 8;           \
            gload_lds16(Wq + q8,        &sW[_d][0][(wv * 2 + j) * 512]);        \
            gload_lds16(Wq + WREG + q8, &sW[_d][1][(wv * 2 + j) * 512]);        \
        }                                                                       \
    }

#define COMPUTE_CHUNK(bufi)                                                     \
    {                                                                           \
        const float*  sAc = sA[bufi];                                           \
        const bf16_t* sWh = sW[bufi][0];                                        \
        const bf16_t* sWl = sW[bufi][1];                                        \
        _Pragma("unroll")                                                       \
        for (int k32 = 0; k32 < 2; ++k32) {                                     \
            int s0 = (k32 * 8 + g * 2) ^ m7;                                    \
            float4 x0 = *(const float4*)&sAc[arow * 64 + s0 * 4];               \
            float4 x1 = *(const float4*)&sAc[arow * 64 + (s0 ^ 1) * 4];         \
            float xs[8] = {x0.x, x0.y, x0.z, x0.w, x1.x, x1.y, x1.z, x1.w};     \
            bf16x8 fAh, fAl;                                                    \
            _Pragma("unroll")                                                   \
            for (int i = 0; i < 8; i++) {                                       \
                bf16_t h = (bf16_t)xs[i];                                       \
                fAh[i] = h; fAl[i] = (bf16_t)(xs[i] - (float)h);                \
            }                                                                   \
            const int q = k32 * 4 + g;                                          \
            {                                                                   \
                int off = (ngrp * 32 + m) * 64 + (q ^ m7) * 8;                  \
                bf16x8 fWh = *(const bf16x8*)&sWh[off];                         \
                bf16x8 fWl = *(const bf16x8*)&sWl[off];                         \
                acc0 = __builtin_amdgcn_mfma_f32_16x16x32_bf16(fAh, fWh, acc0, 0, 0, 0); \
                acc0 = __builtin_amdgcn_mfma_f32_16x16x32_bf16(fAh, fWl, acc0, 0, 0, 0); \
                acc0 = __builtin_amdgcn_mfma_f32_16x16x32_bf16(fAl, fWh, acc0, 0, 0, 0); \
            }                                                                   \
            {                                                                   \
                int off = (ngrp * 32 + 16 + m) * 64 + (q ^ m7) * 8;             \
                bf16x8 fWh = *(const bf16x8*)&sWh[off];                         \
                bf16x8 fWl = *(const bf16x8*)&sWl[off];                         \
                acc1 = __builtin_amdgcn_mfma_f32_16x16x32_bf16(fAh, fWh, acc1, 0, 0, 0); \
                acc1 = __builtin_amdgcn_mfma_f32_16x16x32_bf16(fAh, fWl, acc1, 0, 0, 0); \
                acc1 = __builtin_amdgcn_mfma_f32_16x16x32_bf16(fAl, fWh, acc1, 0, 0, 0); \
            }                                                                   \
        }                                                                       \
    }

    // prologue: fill pipeline 2 deep (12 loads in flight per wave)
    STAGE_CHUNK(0, 0);
    STAGE_CHUNK(1, 1);

    // main loop: chunks 0..13, always 2 stages (12 loads) in flight.
    // per-wave vmcnt(12) ensures THIS wave's chunk-cc loads landed; the
    // s_barrier then ensures ALL waves' chunk-cc loads landed. Trailing
    // barrier protects buffer (cc%3) from next iteration's stage overwrite.
    for (int cc = 0; cc < 14; ++cc) {
        STAGE_CHUNK(cc + 2, (cc + 2) % 3);
        asm volatile("s_waitcnt vmcnt(12)" ::: "memory");
        asm volatile("s_barrier" ::: "memory");
        COMPUTE_CHUNK(cc % 3);
        asm volatile("s_barrier" ::: "memory");
    }
    // epilogue: drain 6 -> 0
    asm volatile("s_waitcnt vmcnt(6)" ::: "memory");
    asm volatile("s_barrier" ::: "memory");
    COMPUTE_CHUNK(2);                      // chunk 14 lives in buffer 14%3=2
    asm volatile("s_waitcnt vmcnt(0)" ::: "memory");
    asm volatile("s_barrier" ::: "memory");
    COMPUTE_CHUNK(0);                      // chunk 15 lives in buffer 15%3=0

    float* pb = part + (size_t)ks * T_TOKENS * 64;
#pragma unroll
    for (int i = 0; i < 4; i++) {
        int t = tok0 + mgrp * 16 + g * 4 + i;     // C: row=(lane>>4)*4+reg
        pb[(size_t)t * 64 + ngrp * 32 + m]      = acc0[i];   // col=lane&15
        pb[(size_t)t * 64 + ngrp * 32 + 16 + m] = acc1[i];
    }
#undef STAGE_CHUNK
#undef COMPUTE_CHUNK
}

// ---------------------------------------------------------------------------
// Kernel 2: persistent sinkhorn, 32 blocks x 256 thr = 1 token/thread.
// Load phase fuses the split-K reduce + logits + sigmoid stores.
// Cross-block sync: publish 64 partials (relaxed-agent) -> release fence ->
// ONE flag store; readers poll 1 flag/lane (32 loads/round, 64x less traffic
// than r3's data-poll), then gather data once. Flags value-signal off 0xAA
// poison (<0).
// ---------------------------------------------------------------------------
__global__ __launch_bounds__(256, 1)
void sinkhorn_v4(const float* __restrict__ part,
                 float* __restrict__ out,
                 float* __restrict__ sd,      // 30*32*64 partial slots
                 float* __restrict__ fl)      // 30*32 flags
{
    __shared__ float tile[4][64 * 68];
    __shared__ float d1_lds[64];
    __shared__ float pl[4][64];
    const int tid = threadIdx.x, bid = blockIdx.x;
    const int wave = tid >> 6, lane = tid & 63;
    const int t = bid * 256 + tid;

    float* logits = out;
    float* aff    = out + (size_t)T_TOKENS * 64;
    float* idx    = out + (size_t)2 * T_TOKENS * 64;

    const float* p0 = part + (size_t)t * 64;
    const float* p1 = part + (size_t)T_TOKENS * 64 + (size_t)t * 64;

    float c[64];
#pragma unroll
    for (int e4 = 0; e4 < 16; e4++) {
        float4 a = *(const float4*)(p0 + e4 * 4);
        float4 b = *(const float4*)(p1 + e4 * 4);
        float4 v = {a.x + b.x, a.y + b.y, a.z + b.z, a.w + b.w};
        *(float4*)(logits + (size_t)t * 64 + e4 * 4) = v;
        float4 sg;
        sg.x = (v.x >= 0.f) ? 1.f / (1.f + expf(-v.x)) : expf(v.x) / (1.f + expf(v.x));
        sg.y = (v.y >= 0.f) ? 1.f / (1.f + expf(-v.y)) : expf(v.y) / (1.f + expf(v.y));
        sg.z = (v.z >= 0.f) ? 1.f / (1.f + expf(-v.z)) : expf(v.z) / (1.f + expf(v.z));
        sg.w = (v.w >= 0.f) ? 1.f / (1.f + expf(-v.w)) : expf(v.w) / (1.f + expf(v.w));
        *(float4*)(aff + (size_t)t * 64 + e4 * 4) = sg;
        c[e4 * 4 + 0] = expf(v.x);
        c[e4 * 4 + 1] = expf(v.y);
        c[e4 * 4 + 2] = expf(v.z);
        c[e4 * 4 + 3] = expf(v.w);
    }
    if (tid < 64) d1_lds[tid] = 1.0f;
    __syncthreads();

    float d0 = 0.f;
    float* tw = tile[wave];

    for (int iter = 0; iter < NITER; ++iter) {
        // phase 1: d0[t] = (1/T) / (sum_e d1[e]*c[e] + eps)
        float s = 0.f;
#pragma unroll
        for (int e4 = 0; e4 < 16; e4++) {
            float4 dv = *(const float4*)(&d1_lds[e4 * 4]);
            s = fmaf(c[e4 * 4 + 0], dv.x, s);
            s = fmaf(c[e4 * 4 + 1], dv.y, s);
            s = fmaf(c[e4 * 4 + 2], dv.z, s);
            s = fmaf(c[e4 * 4 + 3], dv.w, s);
        }
        d0 = (1.0f / 8192.0f) / (s + 1e-8f);

        // phase 2: block-local column sums via per-wave LDS transpose
#pragma unroll
        for (int e4 = 0; e4 < 16; e4++) {
            float4 v;
            v.x = c[e4 * 4 + 0] * d0; v.y = c[e4 * 4 + 1] * d0;
            v.z = c[e4 * 4 + 2] * d0; v.w = c[e4 * 4 + 3] * d0;
            *(float4*)(&tw[lane * 68 + e4 * 4]) = v;
        }
        __syncthreads();
        float colsum = 0.f;
#pragma unroll 16
        for (int j = 0; j < 64; j++) colsum += tw[j * 68 + lane];
        pl[wave][lane] = colsum;
        __syncthreads();

        // cross-block: publish partial + flag; poll flags; gather once
        if (tid < 64) {
            float S = pl[0][tid] + pl[1][tid] + pl[2][tid] + pl[3][tid];
            __hip_atomic_store(&sd[(size_t)(iter * SINK_BLOCKS + bid) * 64 + tid], S,
                               __ATOMIC_RELAXED, __HIP_MEMORY_SCOPE_AGENT);
            if (tid == 0) {
                __builtin_amdgcn_fence(__ATOMIC_RELEASE, "agent");
                __hip_atomic_store(&fl[iter * SINK_BLOCKS + bid], 1.0f,
                                   __ATOMIC_RELAXED, __HIP_MEMORY_SCOPE_AGENT);
            }
            if (tid < SINK_BLOCKS) {
                int guard = 0;
                for (;;) {
                    float f = __hip_atomic_load(&fl[iter * SINK_BLOCKS + tid],
                                                __ATOMIC_RELAXED, __HIP_MEMORY_SCOPE_AGENT);
                    if (f > 0.f || ++guard >= (1 << 20)) break;
                    __builtin_amdgcn_s_sleep(1);
                }
            }
            const float* base = sd + (size_t)iter * SINK_BLOCKS * 64 + tid;
            float v[SINK_BLOCKS];
#pragma unroll
            for (int b = 0; b < SINK_BLOCKS; b++)
                v[b] = __hip_atomic_load(base + b * 64, __ATOMIC_RELAXED,
                                         __HIP_MEMORY_SCOPE_AGENT);
            float S2 = 0.f;
#pragma unroll
            for (int b = 0; b < SINK_BLOCKS; b++) S2 += v[b];
            d1_lds[tid] = (1.0f / 64.0f) / (S2 + 1e-8f);
        }
        __syncthreads();
    }

    // argmax_e of d1[e]*c[e]*d0 (first max wins, like jnp.argmax)
    float best = -1.0f; int bi = 0;
#pragma unroll
    for (int e4 = 0; e4 < 16; e4++) {
        float4 dv = *(const float4*)(&d1_lds[e4 * 4]);
        float vv0 = (dv.x * c[e4 * 4 + 0]) * d0;
        float vv1 = (dv.y * c[e4 * 4 + 1]) * d0;
        float vv2 = (dv.z * c[e4 * 4 + 2]) * d0;
        float vv3 = (dv.w * c[e4 * 4 + 3]) * d0;
        if (vv0 > best) { best = vv0; bi = e4 * 4 + 0; }
        if (vv1 > best) { best = vv1; bi = e4 * 4 + 1; }
        if (vv2 > best) { best = vv2; bi = e4 * 4 + 2; }
        if (vv3 > best) { best = vv3; bi = e4 * 4 + 3; }
    }
    idx[t] = (float)bi;
}

extern "C" void kernel_launch(void* const* d_in, const int* in_sizes, int n_in,
                              void* d_out, int out_size, void* d_ws, size_t ws_size,
                              hipStream_t stream)
{
    (void)in_sizes; (void)n_in; (void)out_size; (void)ws_size;
    const float* hs = (const float*)d_in[0];   // 8192 x 2048 f32
    const float* W  = (const float*)d_in[1];   // 64 x 2048 f32
    float* out      = (float*)d_out;           // [logits | affinities | idx]

    bf16_t* wsw = (bf16_t*)d_ws;               // 512 KB prepped W (hi|lo)
    float*  part = (float*)d_ws + 131072;      // 4 MB: part[2][8192][64]
    float*  sd   = part + 2 * T_TOKENS * 64;   // 240 KB sink partial slots
    float*  fl   = sd + NITER * SINK_BLOCKS * 64;  // flags

    prep_whl<<<128, 256, 0, stream>>>(W, wsw);
    gemm_splitk<<<512, 256, 0, stream>>>(hs, wsw, part);
    sinkhorn_v4<<<SINK_BLOCKS, 256, 0, stream>>>(part, out, sd, fl);
}

// Round 2
// 212.643 us; speedup vs baseline: 1.0363x; 1.0363x over previous
//
#include <hip/hip_runtime.h>
#include <math.h>

#define T_TOKENS 8192
#define NEXP 64
#define HID 2048
#define NITER 30
#define SINK_BLOCKS 32
#define WREG 131072          // bf16 elements per W region (64 x 2048)
#define FLPAD 32             // floats per flag slot (128 B, own cache line)

typedef __bf16 bf16_t;
typedef bf16_t bf16x8 __attribute__((ext_vector_type(8)));
typedef float  f32x4  __attribute__((ext_vector_type(4)));

__device__ __forceinline__ void gload_lds16(const void* g, void* l) {
    __builtin_amdgcn_global_load_lds(
        (const __attribute__((address_space(1))) unsigned int*)g,
        (__attribute__((address_space(3))) unsigned int*)l, 16, 0, 0);
}

// ---------------------------------------------------------------------------
// Kernel 0: W (64x2048 f32) -> hi/lo bf16, per-64k-chunk quad-XOR-swizzled,
// linear in the exact order gemm's global_load_lds consumes.
// chunk c (0..31), row r, slot s holds quad q = s ^ (r&7) of W[r][c*64..].
// ---------------------------------------------------------------------------
__global__ __launch_bounds__(256)
void prep_whl(const float* __restrict__ W, bf16_t* __restrict__ wsw)
{
    int gid = blockIdx.x * 256 + threadIdx.x;   // 0..32767
    int region = gid >> 14;                     // 0 = hi, 1 = lo
    int qid = gid & 16383;
    int c = qid >> 9, L = qid & 511;
    int r = L >> 3, slot = L & 7;
    int qi = slot ^ (r & 7);
    const float* src = W + (size_t)r * HID + c * 64 + qi * 8;
    float4 v0 = *(const float4*)src;
    float4 v1 = *(const float4*)(src + 4);
    float x[8] = {v0.x, v0.y, v0.z, v0.w, v1.x, v1.y, v1.z, v1.w};
    bf16x8 q;
#pragma unroll
    for (int i = 0; i < 8; i++) {
        bf16_t h = (bf16_t)x[i];
        q[i] = (region == 0) ? h : (bf16_t)(x[i] - (float)h);
    }
    *(bf16x8*)(wsw + (size_t)region * WREG + (size_t)qid * 8) = q;
}

// ---------------------------------------------------------------------------
// Kernel 1: split-K(2) MFMA GEMM. 512 blocks x 256 thr (4 waves).
// Block: 32 tokens x 64 experts x K-half 1024 (16 chunks of 64).
// ALL staging via global_load_lds(16B): A raw f32 (source-address swizzled),
// W prepped bf16. Wave (mgrp,ngrp) = 16 tok x 32 exp; 3-term split-bf16 MFMA.
// Depth-2 prefetch (3 LDS buffers), raw s_barrier + counted vmcnt.
// NOTE r2: pipeline restructure (r1) was NEUTRAL -> GEMM is not
// barrier/latency-bound. Working theory: DRAM page/bank conflicts from the
// 256B-per-8KB-stride A sweep. UNCHANGED this round; next round's top-5
// counters (once sinkhorn < gemm) will show gemm FETCH_SIZE/hbm_gbps to
// confirm before a tile redesign.
// ---------------------------------------------------------------------------
__global__ __launch_bounds__(256, 2)
void gemm_splitk(const float* __restrict__ A, const bf16_t* __restrict__ Wq,
                 float* __restrict__ part)
{
    __shared__ float  sA[3][32 * 64];       // 8 KB x3 (raw f32, swizzled chunks)
    __shared__ bf16_t sW[3][2][64 * 64];    // 8 KB x6 (hi/lo bf16, swizzled)

    const int tid = threadIdx.x, lane = tid & 63, wv = tid >> 6;
    const int ks   = blockIdx.x & 1;
    const int tok0 = (blockIdx.x >> 1) * 32;
    const int mgrp = wv >> 1, ngrp = wv & 1;
    const int g = lane >> 4, m = lane & 15;
    const int arow = mgrp * 16 + m;
    const int m7 = m & 7;

    f32x4 acc0 = {0.f, 0.f, 0.f, 0.f}, acc1 = {0.f, 0.f, 0.f, 0.f};

    // staging maps (2 A-instrs + 4 W-instrs per wave per chunk)
    int ap[2], acs[2];   // A: lds position block, swizzled source chunk
#pragma unroll
    for (int j = 0; j < 2; j++) {
        int p = (wv * 2 + j) * 64 + lane;          // 16B-position 0..511
        ap[j] = p;
        int r = p >> 4, slot = p & 15;
        acs[j] = slot ^ (r & 7);                   // source 16B-chunk within row
    }

#define STAGE_CHUNK(cc, dst)                                                    \
    {                                                                           \
        const int _cc = (cc);                                                   \
        const int _d  = (dst);                                                  \
        _Pragma("unroll")                                                       \
        for (int j = 0; j < 2; j++) {                                           \
            int r = ap[j] >> 4;                                                 \
            const float* src = A + (size_t)(tok0 + r) * HID + ks * 1024         \
                             + _cc * 64 + acs[j] * 4;                           \
            gload_lds16(src, &sA[_d][(wv * 2 + j) * 256]);                      \
        }                                                                       \
        const size_t chb = ((size_t)(ks * 16 + _cc) * 512) * 8;                 \
        _Pragma("unroll")                                                       \
        for (int j = 0; j < 2; j++) {                                           \
            size_t q8 = chb + (size_t)((wv * 2 + j) * 64 + lane) * 8;           \
            gload_lds16(Wq + q8,        &sW[_d][0][(wv * 2 + j) * 512]);        \
            gload_lds16(Wq + WREG + q8, &sW[_d][1][(wv * 2 + j) * 512]);        \
        }                                                                       \
    }

#define COMPUTE_CHUNK(bufi)                                                     \
    {                                                                           \
        const float*  sAc = sA[bufi];                                           \
        const bf16_t* sWh = sW[bufi][0];                                        \
        const bf16_t* sWl = sW[bufi][1];                                        \
        _Pragma("unroll")                                                       \
        for (int k32 = 0; k32 < 2; ++k32) {                                     \
            int s0 = (k32 * 8 + g * 2) ^ m7;                                    \
            float4 x0 = *(const float4*)&sAc[arow * 64 + s0 * 4];               \
            float4 x1 = *(const float4*)&sAc[arow * 64 + (s0 ^ 1) * 4];         \
            float xs[8] = {x0.x, x0.y, x0.z, x0.w, x1.x, x1.y, x1.z, x1.w};     \
            bf16x8 fAh, fAl;                                                    \
            _Pragma("unroll")                                                   \
            for (int i = 0; i < 8; i++) {                                       \
                bf16_t h = (bf16_t)xs[i];                                       \
                fAh[i] = h; fAl[i] = (bf16_t)(xs[i] - (float)h);                \
            }                                                                   \
            const int q = k32 * 4 + g;                                          \
            {                                                                   \
                int off = (ngrp * 32 + m) * 64 + (q ^ m7) * 8;                  \
                bf16x8 fWh = *(const bf16x8*)&sWh[off];                         \
                bf16x8 fWl = *(const bf16x8*)&sWl[off];                         \
                acc0 = __builtin_amdgcn_mfma_f32_16x16x32_bf16(fAh, fWh, acc0, 0, 0, 0); \
                acc0 = __builtin_amdgcn_mfma_f32_16x16x32_bf16(fAh, fWl, acc0, 0, 0, 0); \
                acc0 = __builtin_amdgcn_mfma_f32_16x16x32_bf16(fAl, fWh, acc0, 0, 0, 0); \
            }                                                                   \
            {                                                                   \
                int off = (ngrp * 32 + 16 + m) * 64 + (q ^ m7) * 8;             \
                bf16x8 fWh = *(const bf16x8*)&sWh[off];                         \
                bf16x8 fWl = *(const bf16x8*)&sWl[off];                         \
                acc1 = __builtin_amdgcn_mfma_f32_16x16x32_bf16(fAh, fWh, acc1, 0, 0, 0); \
                acc1 = __builtin_amdgcn_mfma_f32_16x16x32_bf16(fAh, fWl, acc1, 0, 0, 0); \
                acc1 = __builtin_amdgcn_mfma_f32_16x16x32_bf16(fAl, fWh, acc1, 0, 0, 0); \
            }                                                                   \
        }                                                                       \
    }

    // prologue: fill pipeline 2 deep (12 loads in flight per wave)
    STAGE_CHUNK(0, 0);
    STAGE_CHUNK(1, 1);

    for (int cc = 0; cc < 14; ++cc) {
        STAGE_CHUNK(cc + 2, (cc + 2) % 3);
        asm volatile("s_waitcnt vmcnt(12)" ::: "memory");
        asm volatile("s_barrier" ::: "memory");
        COMPUTE_CHUNK(cc % 3);
        asm volatile("s_barrier" ::: "memory");
    }
    asm volatile("s_waitcnt vmcnt(6)" ::: "memory");
    asm volatile("s_barrier" ::: "memory");
    COMPUTE_CHUNK(2);                      // chunk 14 -> buffer 14%3=2
    asm volatile("s_waitcnt vmcnt(0)" ::: "memory");
    asm volatile("s_barrier" ::: "memory");
    COMPUTE_CHUNK(0);                      // chunk 15 -> buffer 15%3=0

    float* pb = part + (size_t)ks * T_TOKENS * 64;
#pragma unroll
    for (int i = 0; i < 4; i++) {
        int t = tok0 + mgrp * 16 + g * 4 + i;     // C: row=(lane>>4)*4+reg
        pb[(size_t)t * 64 + ngrp * 32 + m]      = acc0[i];   // col=lane&15
        pb[(size_t)t * 64 + ngrp * 32 + 16 + m] = acc1[i];
    }
#undef STAGE_CHUNK
#undef COMPUTE_CHUNK
}

// ---------------------------------------------------------------------------
// Kernel 2: persistent sinkhorn, 32 blocks x 256 thr = 1 token/thread.
// r2 change: flags padded to one 128-B line each (FLPAD floats). Previously
// all 32 per-iteration flags shared 2 cache lines -> 32 cross-XCD stores +
// 1024 polling lanes serialized on line ownership at the coherence point
// (~3.8 us/iter, 0.85% HBM, 1.7% VALU = pure sync latency). Now each block's
// flag store is line-exclusive and each poller lane reads its own line.
// ---------------------------------------------------------------------------
__global__ __launch_bounds__(256, 1)
void sinkhorn_v4(const float* __restrict__ part,
                 float* __restrict__ out,
                 float* __restrict__ sd,      // 30*32*64 partial slots
                 float* __restrict__ fl)      // 30*32 flags, FLPAD-padded
{
    __shared__ float tile[4][64 * 68];
    __shared__ float d1_lds[64];
    __shared__ float pl[4][64];
    const int tid = threadIdx.x, bid = blockIdx.x;
    const int wave = tid >> 6, lane = tid & 63;
    const int t = bid * 256 + tid;

    float* logits = out;
    float* aff    = out + (size_t)T_TOKENS * 64;
    float* idx    = out + (size_t)2 * T_TOKENS * 64;

    const float* p0 = part + (size_t)t * 64;
    const float* p1 = part + (size_t)T_TOKENS * 64 + (size_t)t * 64;

    float c[64];
#pragma unroll
    for (int e4 = 0; e4 < 16; e4++) {
        float4 a = *(const float4*)(p0 + e4 * 4);
        float4 b = *(const float4*)(p1 + e4 * 4);
        float4 v = {a.x + b.x, a.y + b.y, a.z + b.z, a.w + b.w};
        *(float4*)(logits + (size_t)t * 64 + e4 * 4) = v;
        float4 sg;
        sg.x = (v.x >= 0.f) ? 1.f / (1.f + expf(-v.x)) : expf(v.x) / (1.f + expf(v.x));
        sg.y = (v.y >= 0.f) ? 1.f / (1.f + expf(-v.y)) : expf(v.y) / (1.f + expf(v.y));
        sg.z = (v.z >= 0.f) ? 1.f / (1.f + expf(-v.z)) : expf(v.z) / (1.f + expf(v.z));
        sg.w = (v.w >= 0.f) ? 1.f / (1.f + expf(-v.w)) : expf(v.w) / (1.f + expf(v.w));
        *(float4*)(aff + (size_t)t * 64 + e4 * 4) = sg;
        c[e4 * 4 + 0] = expf(v.x);
        c[e4 * 4 + 1] = expf(v.y);
        c[e4 * 4 + 2] = expf(v.z);
        c[e4 * 4 + 3] = expf(v.w);
    }
    if (tid < 64) d1_lds[tid] = 1.0f;
    __syncthreads();

    float d0 = 0.f;
    float* tw = tile[wave];

    for (int iter = 0; iter < NITER; ++iter) {
        // phase 1: d0[t] = (1/T) / (sum_e d1[e]*c[e] + eps)
        float s = 0.f;
#pragma unroll
        for (int e4 = 0; e4 < 16; e4++) {
            float4 dv = *(const float4*)(&d1_lds[e4 * 4]);
            s = fmaf(c[e4 * 4 + 0], dv.x, s);
            s = fmaf(c[e4 * 4 + 1], dv.y, s);
            s = fmaf(c[e4 * 4 + 2], dv.z, s);
            s = fmaf(c[e4 * 4 + 3], dv.w, s);
        }
        d0 = (1.0f / 8192.0f) / (s + 1e-8f);

        // phase 2: block-local column sums via per-wave LDS transpose
#pragma unroll
        for (int e4 = 0; e4 < 16; e4++) {
            float4 v;
            v.x = c[e4 * 4 + 0] * d0; v.y = c[e4 * 4 + 1] * d0;
            v.z = c[e4 * 4 + 2] * d0; v.w = c[e4 * 4 + 3] * d0;
            *(float4*)(&tw[lane * 68 + e4 * 4]) = v;
        }
        __syncthreads();
        float colsum = 0.f;
#pragma unroll 16
        for (int j = 0; j < 64; j++) colsum += tw[j * 68 + lane];
        pl[wave][lane] = colsum;
        __syncthreads();

        // cross-block: publish partial + flag; poll flags; gather once
        if (tid < 64) {
            float S = pl[0][tid] + pl[1][tid] + pl[2][tid] + pl[3][tid];
            __hip_atomic_store(&sd[(size_t)(iter * SINK_BLOCKS + bid) * 64 + tid], S,
                               __ATOMIC_RELAXED, __HIP_MEMORY_SCOPE_AGENT);
            if (tid == 0) {
                __builtin_amdgcn_fence(__ATOMIC_RELEASE, "agent");
                __hip_atomic_store(&fl[(size_t)(iter * SINK_BLOCKS + bid) * FLPAD], 1.0f,
                                   __ATOMIC_RELAXED, __HIP_MEMORY_SCOPE_AGENT);
            }
            if (tid < SINK_BLOCKS) {
                int guard = 0;
                for (;;) {
                    float f = __hip_atomic_load(&fl[(size_t)(iter * SINK_BLOCKS + tid) * FLPAD],
                                                __ATOMIC_RELAXED, __HIP_MEMORY_SCOPE_AGENT);
                    if (f > 0.f || ++guard >= (1 << 20)) break;
                    __builtin_amdgcn_s_sleep(1);
                }
            }
            const float* base = sd + (size_t)iter * SINK_BLOCKS * 64 + tid;
            float v[SINK_BLOCKS];
#pragma unroll
            for (int b = 0; b < SINK_BLOCKS; b++)
                v[b] = __hip_atomic_load(base + b * 64, __ATOMIC_RELAXED,
                                         __HIP_MEMORY_SCOPE_AGENT);
            float S2 = 0.f;
#pragma unroll
            for (int b = 0; b < SINK_BLOCKS; b++) S2 += v[b];
            d1_lds[tid] = (1.0f / 64.0f) / (S2 + 1e-8f);
        }
        __syncthreads();
    }

    // argmax_e of d1[e]*c[e]*d0 (first max wins, like jnp.argmax)
    float best = -1.0f; int bi = 0;
#pragma unroll
    for (int e4 = 0; e4 < 16; e4++) {
        float4 dv = *(const float4*)(&d1_lds[e4 * 4]);
        float vv0 = (dv.x * c[e4 * 4 + 0]) * d0;
        float vv1 = (dv.y * c[e4 * 4 + 1]) * d0;
        float vv2 = (dv.z * c[e4 * 4 + 2]) * d0;
        float vv3 = (dv.w * c[e4 * 4 + 3]) * d0;
        if (vv0 > best) { best = vv0; bi = e4 * 4 + 0; }
        if (vv1 > best) { best = vv1; bi = e4 * 4 + 1; }
        if (vv2 > best) { best = vv2; bi = e4 * 4 + 2; }
        if (vv3 > best) { best = vv3; bi = e4 * 4 + 3; }
    }
    idx[t] = (float)bi;
}

extern "C" void kernel_launch(void* const* d_in, const int* in_sizes, int n_in,
                              void* d_out, int out_size, void* d_ws, size_t ws_size,
                              hipStream_t stream)
{
    (void)in_sizes; (void)n_in; (void)out_size; (void)ws_size;
    const float* hs = (const float*)d_in[0];   // 8192 x 2048 f32
    const float* W  = (const float*)d_in[1];   // 64 x 2048 f32
    float* out      = (float*)d_out;           // [logits | affinities | idx]

    bf16_t* wsw = (bf16_t*)d_ws;               // 512 KB prepped W (hi|lo)
    float*  part = (float*)d_ws + 131072;      // 4 MB: part[2][8192][64]
    float*  sd   = part + 2 * T_TOKENS * 64;   // 240 KB sink partial slots
    float*  fl   = sd + NITER * SINK_BLOCKS * 64;  // padded flags (120 KB)

    prep_whl<<<128, 256, 0, stream>>>(W, wsw);
    gemm_splitk<<<512, 256, 0, stream>>>(hs, wsw, part);
    sinkhorn_v4<<<SINK_BLOCKS, 256, 0, stream>>>(part, out, sd, fl);
}